// Round 12
// baseline (322.919 us; speedup 1.0000x reference)
//
#include <hip/hip_runtime.h>

// CRF forward-score + gold-score, MI355X (gfx950).
//
// R16 = R14 machinery (exact; R15's stale-normalizer+split reverted — it
// was neutral and cost 12 VGPR) with two TLP-directed changes:
//  1. SEGLEN 16, NJ 31: chain 32 -> 16 steps; 2048 blocks = 4096 waves
//     = 4 waves/SIMD (R13->R14 showed waves/SIMD is the lever that
//     works: 0.875->2 gave 1.27x; critical-path surgery gave 0x twice).
//     VGPR must stay <= 128 for 4/SIMD: launch_bounds(128,4), R14's
//     machinery measured 120. Rank-1 contrast at L=16 ~ 1e-12 (fp32-
//     exact; L=32 measured absmax 0.0 with huge margin).
//  2. E-fragment PRECOMPUTE: 1-block prep kernel does the scattered
//     trans-gather + expf + hi/lo split ONCE for both DIR and stores the
//     exact register images (32 KB) to workspace; chain blocks reload
//     them as 16 coalesced dwordx4 (lane-stride 16 B). Kills the per-
//     block prologue that NJ=31 would otherwise double.
//
// R13/R14 (verified absmax 0.0): rank-1 segment split.
//   f_s = P_s u_s (u_1 = e_START else 1),  g_s = P_s^T 1,
//   score = sum_j log(g_{j+1}^T f_j) - sum_{j>=2} log(1^T f_j)
//           (+ exact 2^esum bookkeeping) - gold
// Block (grp,j): wave0 = f_j fwd, wave1 = g_{j+1} bwd, LDS meet,
// atomicAdd diff[b]. Gold in 64 dedicated blocks.
//
// Per-step machinery (verified R11-R14, absmax 0.0): z[64x16] = E*w on
// the matrix pipe, 16 chains/wave as columns, 4 row-tiles x 2 K-slabs
// mfma_f32_16x16x32_f16, SPLIT-F16 (z = Ehi*whi + Elo*whi + Ehi*wlo, 24
// MFMA/step); C/D layout col=lane&15,row=4*(lane>>4)+reg; A/B share the
// (h,e)->k bijection; C layout == B layout -> zero cross-lane recurrence;
// per-column max-exponent normalization + exact int esum; feat ring
// depth 4.

#define BB 1024
#define TT 512
#define KK 64
#define GB 16
#define NJ 31         // junctions (32 segments)
#define SEGLEN 16
#define LN2F 0.6931471805599453f

typedef _Float16 f16;
typedef f16   f16x8 __attribute__((ext_vector_type(8)));
typedef float f32x4 __attribute__((ext_vector_type(4)));

union W8 { f16x8 v; f16 e[8]; uint4 u; };

#define MFMA16(A, B, C) __builtin_amdgcn_mfma_f32_16x16x32_f16((A), (B), (C), 0, 0, 0)

__device__ __forceinline__ f32x4 exp4(f32x4 u) {
  f32x4 r; r.x = __expf(u.x); r.y = __expf(u.y); r.z = __expf(u.z); r.w = __expf(u.w);
  return r;
}

__device__ __forceinline__ unsigned umaxu(unsigned a, unsigned b) { return a > b ? a : b; }

// per-column max-exponent normalization: v = q * 2^-e, esum += e (tree max)
__device__ __forceinline__ void normalize(const f32x4 (&q)[4], f32x4 (&v)[4], int& esum) {
  unsigned t0 = umaxu(umaxu(__float_as_uint(q[0].x), __float_as_uint(q[0].y)),
                      umaxu(__float_as_uint(q[0].z), __float_as_uint(q[0].w)));
  unsigned t1 = umaxu(umaxu(__float_as_uint(q[1].x), __float_as_uint(q[1].y)),
                      umaxu(__float_as_uint(q[1].z), __float_as_uint(q[1].w)));
  unsigned t2 = umaxu(umaxu(__float_as_uint(q[2].x), __float_as_uint(q[2].y)),
                      umaxu(__float_as_uint(q[2].z), __float_as_uint(q[2].w)));
  unsigned t3 = umaxu(umaxu(__float_as_uint(q[3].x), __float_as_uint(q[3].y)),
                      umaxu(__float_as_uint(q[3].z), __float_as_uint(q[3].w)));
  unsigned mb = umaxu(umaxu(t0, t1), umaxu(t2, t3));
  mb = umaxu(mb, (unsigned)__shfl_xor((int)mb, 16));
  mb = umaxu(mb, (unsigned)__shfl_xor((int)mb, 32));
  esum += (int)(mb >> 23) - 127;
  const float s = __uint_as_float(0x7F000000u - (mb & 0x7F800000u));
  #pragma unroll
  for (int tau = 0; tau < 4; ++tau) v[tau] = q[tau] * s;
}

// split-f16 pack: element e of slab S = v[2S + (e>>2)][e&3] (matches A k-map)
__device__ __forceinline__ void pack_w(const f32x4 (&v)[4], W8 (&whi)[2], W8 (&wlo)[2]) {
  #pragma unroll
  for (int S = 0; S < 2; ++S) {
    #pragma unroll
    for (int c = 0; c < 2; ++c) {
      const f32x4 t = v[2 * S + c];
      const f16 h0 = (f16)t.x, h1 = (f16)t.y, h2 = (f16)t.z, h3 = (f16)t.w;
      whi[S].e[4 * c + 0] = h0;
      whi[S].e[4 * c + 1] = h1;
      whi[S].e[4 * c + 2] = h2;
      whi[S].e[4 * c + 3] = h3;
      wlo[S].e[4 * c + 0] = (f16)(t.x - (float)h0);
      wlo[S].e[4 * c + 1] = (f16)(t.y - (float)h1);
      wlo[S].e[4 * c + 2] = (f16)(t.z - (float)h2);
      wlo[S].e[4 * c + 3] = (f16)(t.w - (float)h3);
    }
  }
}

// one recurrence step: z = E*w (24 MFMA, split-3)
__device__ __forceinline__ void mfma_step(const W8 (&Ehi)[4][2], const W8 (&Elo)[4][2],
                                          const W8 (&whi)[2], const W8 (&wlo)[2],
                                          f32x4 (&acc)[4]) {
  #pragma unroll
  for (int tau = 0; tau < 4; ++tau) {
    f32x4 a = {0.f, 0.f, 0.f, 0.f};
    a = MFMA16(Ehi[tau][0].v, whi[0].v, a);
    a = MFMA16(Ehi[tau][1].v, whi[1].v, a);
    a = MFMA16(Elo[tau][0].v, whi[0].v, a);
    a = MFMA16(Elo[tau][1].v, whi[1].v, a);
    a = MFMA16(Ehi[tau][0].v, wlo[0].v, a);
    a = MFMA16(Ehi[tau][1].v, wlo[1].v, a);
    acc[tau] = a;
  }
}

// one chain step with compile-time ring slot D (runtime j only in addresses)
template <int DIR, int D>
__device__ __forceinline__ void step_one(
    const float* __restrict__ fB, int j, int t_lo, int t_hi,
    const W8 (&Ehi)[4][2], const W8 (&Elo)[4][2],
    W8 (&whi)[2], W8 (&wlo)[2],
    f32x4 (&uR)[4][4], f32x4 (&g)[4],
    f32x4 (&v)[4], int& esum)
{
  f32x4 acc[4];
  mfma_step(Ehi, Elo, whi, wlo, acc);

  // refill slot D with this chain's step j+4 (clamped; clamped dups unused)
  int tn = DIR ? (t_hi - 1 - (j + 4)) : (t_lo + (j + 4));
  if (DIR) { if (tn < t_lo) tn = t_lo; } else { if (tn > t_hi) tn = t_hi; }
  #pragma unroll
  for (int tau = 0; tau < 4; ++tau)
    uR[D][tau] = *(const f32x4*)(fB + (size_t)tn * KK + 16 * tau);

  f32x4 q[4];
  #pragma unroll
  for (int tau = 0; tau < 4; ++tau) q[tau] = acc[tau] * g[tau];
  normalize(q, v, esum);
  pack_w(v, whi, wlo);

  constexpr int DN = (D + 1) & 3;
  #pragma unroll
  for (int tau = 0; tau < 4; ++tau) g[tau] = exp4(uR[DN][tau]);
}

// DIR=0: f = prod_{t=t_lo..t_hi ascending}(D_t E) u   (nstep steps)
// DIR=1: g = E^T D_{t_lo} ... E^T D_{t_hi} 1          (nstep loop + tail)
template <int DIR>
__device__ __forceinline__ void run_seg(
    const float* __restrict__ feats, const uint4* __restrict__ frags,
    int grp, int lane, int t_lo, int t_hi, int nstep, int one_hot,
    f32x4 (&v)[4], int& esum)
{
  const int m = lane & 15;
  const int h = lane >> 4;

  // ---- E fragments: coalesced reload of the precomputed register image
  W8 Ehi[4][2], Elo[4][2];
  {
    const uint4* fr = frags + DIR * 1024 + lane;
    #pragma unroll
    for (int tau = 0; tau < 4; ++tau)
      #pragma unroll
      for (int S = 0; S < 2; ++S) {
        Ehi[tau][S].u = fr[(tau * 2 + S) * 64];
        Elo[tau][S].u = fr[(8 + tau * 2 + S) * 64];
      }
  }

  const float* fB = feats + (size_t)(grp * GB + m) * TT * KK + 4 * h;

  // ---- feat ring, depth 4 (3 windows of slack)
  f32x4 uR[4][4];
  #pragma unroll
  for (int d = 0; d < 4; ++d) {
    int t = DIR ? (t_hi - 1 - d) : (t_lo + d);
    if (DIR) { if (t < t_lo) t = t_lo; } else { if (t > t_hi) t = t_hi; }
    #pragma unroll
    for (int tau = 0; tau < 4; ++tau)
      uR[d][tau] = *(const f32x4*)(fB + (size_t)t * KK + 16 * tau);
  }

  W8 whi[2], wlo[2];
  f32x4 g[4];
  esum = 0;

  if (DIR == 0) {
    f32x4 vv[4];
    if (one_hot) {
      #pragma unroll
      for (int tau = 0; tau < 4; ++tau) vv[tau] = (f32x4){0.f, 0.f, 0.f, 0.f};
      if (h == 3) vv[3].z = 1.0f;   // row 62 = 16*3 + 4*3 + 2 (START)
    } else {
      #pragma unroll
      for (int tau = 0; tau < 4; ++tau) vv[tau] = (f32x4){1.f, 1.f, 1.f, 1.f};
    }
    pack_w(vv, whi, wlo);
  } else {
    f32x4 q[4];
    #pragma unroll
    for (int tau = 0; tau < 4; ++tau)
      q[tau] = exp4(*(const f32x4*)(fB + (size_t)t_hi * KK + 16 * tau));
    normalize(q, v, esum);          // w0 = pack(exp(u_{t_hi})), normalized
    pack_w(v, whi, wlo);
  }
  #pragma unroll
  for (int tau = 0; tau < 4; ++tau) g[tau] = exp4(uR[0][tau]);

  const int nq = nstep >> 2;
  for (int gg = 0; gg < nq; ++gg) {
    const int j = 4 * gg;
    step_one<DIR, 0>(fB, j + 0, t_lo, t_hi, Ehi, Elo, whi, wlo, uR, g, v, esum);
    step_one<DIR, 1>(fB, j + 1, t_lo, t_hi, Ehi, Elo, whi, wlo, uR, g, v, esum);
    step_one<DIR, 2>(fB, j + 2, t_lo, t_hi, Ehi, Elo, whi, wlo, uR, g, v, esum);
    step_one<DIR, 3>(fB, j + 3, t_lo, t_hi, Ehi, Elo, whi, wlo, uR, g, v, esum);
  }
  const int jr = 4 * nq;
  const int rem = nstep & 3;
  if (rem > 0) step_one<DIR, 0>(fB, jr + 0, t_lo, t_hi, Ehi, Elo, whi, wlo, uR, g, v, esum);
  if (rem > 1) step_one<DIR, 1>(fB, jr + 1, t_lo, t_hi, Ehi, Elo, whi, wlo, uR, g, v, esum);
  if (rem > 2) step_one<DIR, 2>(fB, jr + 2, t_lo, t_hi, Ehi, Elo, whi, wlo, uR, g, v, esum);

  if (DIR == 1) {                   // tail: final E^T, no D
    f32x4 acc[4];
    mfma_step(Ehi, Elo, whi, wlo, acc);
    normalize(acc, v, esum);
  }
}

__global__ void zero_diff_kernel(float* __restrict__ diff) {
  diff[threadIdx.x] = 0.0f;
}

// 1-block prep: compute E/E^T fragment register images (hi/lo) for all
// lanes, store to workspace in the exact load pattern (lane-stride 16 B).
__global__ __launch_bounds__(128) void prep_kernel(
    const float* __restrict__ trans, uint4* __restrict__ frags)
{
  const int lane = threadIdx.x & 63;
  const int DIR  = threadIdx.x >> 6;
  const int m = lane & 15;
  const int h = lane >> 4;

  W8 Ehi[4][2], Elo[4][2];
  #pragma unroll
  for (int tau = 0; tau < 4; ++tau)
    #pragma unroll
    for (int S = 0; S < 2; ++S)
      #pragma unroll
      for (int e = 0; e < 8; ++e) {
        const int kk = 32 * S + 16 * (e >> 2) + 4 * h + (e & 3);
        const int row = 16 * tau + m;
        const float val = __expf(DIR ? trans[kk * KK + row] : trans[row * KK + kk]);
        const f16 hi = (f16)val;
        Ehi[tau][S].e[e] = hi;
        Elo[tau][S].e[e] = (f16)(val - (float)hi);
      }

  uint4* fr = frags + DIR * 1024 + lane;
  #pragma unroll
  for (int tau = 0; tau < 4; ++tau)
    #pragma unroll
    for (int S = 0; S < 2; ++S) {
      fr[(tau * 2 + S) * 64]     = Ehi[tau][S].u;
      fr[(8 + tau * 2 + S) * 64] = Elo[tau][S].u;
    }
}

__global__ __launch_bounds__(128, 4) void crf_seg_kernel(
    const float* __restrict__ feats,   // [B, T, K]
    const int*   __restrict__ tags,    // [B, T]
    const float* __restrict__ trans,   // [K, K]  trans[i*K+j] = score j -> i
    const uint4* __restrict__ frags,   // precomputed E fragment images
    float*       __restrict__ diff)    // [B]  forward - gold (accumulated)
{
  __shared__ float ysh[KK][GB];
  __shared__ int   esum_sh[GB];
  __shared__ float gpart[GB];

  const int chainBlocks = 64 * NJ;

  if ((int)blockIdx.x < chainBlocks) {
    // ================= chain block (grp, junction j) =================
    const int lane = threadIdx.x & 63;
    const int wv   = threadIdx.x >> 6;
    const int grp  = blockIdx.x / NJ;        // 0..63 (16 batches each)
    const int j    = 1 + blockIdx.x % NJ;    // junction 1..NJ
    const int m = lane & 15;
    const int h = lane >> 4;

    f32x4 v[4];
    int esum;

    if (wv == 1) {
      // g_{j+1}: bwd over segment j+1 = [SEGLEN*j+1 .. min(SEGLEN*(j+1), 511)]
      const int t_lo = SEGLEN * j + 1;
      const int t_hi = (j == NJ) ? (TT - 1) : SEGLEN * (j + 1);
      run_seg<1>(feats, frags, grp, lane, t_lo, t_hi, t_hi - t_lo, 0, v, esum);
      #pragma unroll
      for (int tau = 0; tau < 4; ++tau) {
        ysh[16 * tau + 4 * h + 0][m] = v[tau].x;
        ysh[16 * tau + 4 * h + 1][m] = v[tau].y;
        ysh[16 * tau + 4 * h + 2][m] = v[tau].z;
        ysh[16 * tau + 4 * h + 3][m] = v[tau].w;
      }
      if (lane < 16) esum_sh[lane] = esum;
      __syncthreads();
    } else {
      // f_j: fwd over segment j; one-hot start iff j==1
      const int t_lo = SEGLEN * (j - 1) + 1;
      const int t_hi = SEGLEN * j;
      run_seg<0>(feats, frags, grp, lane, t_lo, t_hi, SEGLEN, j == 1, v, esum);

      __syncthreads();

      // ---- junction dots: A = g~^T f~ ; Bs = 1^T f~  (per column m)
      float A = 0.f, Bs = 0.f;
      #pragma unroll
      for (int tau = 0; tau < 4; ++tau) {
        A += v[tau].x * ysh[16 * tau + 4 * h + 0][m];
        A += v[tau].y * ysh[16 * tau + 4 * h + 1][m];
        A += v[tau].z * ysh[16 * tau + 4 * h + 2][m];
        A += v[tau].w * ysh[16 * tau + 4 * h + 3][m];
        Bs += (v[tau].x + v[tau].y) + (v[tau].z + v[tau].w);
      }
      A  += __shfl_xor(A, 16);  A  += __shfl_xor(A, 32);
      Bs += __shfl_xor(Bs, 16); Bs += __shfl_xor(Bs, 32);

      if (lane < 16) {
        // c_j = log(A) + (ef+eg)ln2 - [j>1](log(Bs) + ef*ln2)
        float c = __logf(A) + (float)(esum + esum_sh[lane]) * LN2F;
        if (j > 1) c -= __logf(Bs) + (float)esum * LN2F;
        atomicAdd(&diff[grp * GB + lane], c);
      }
    }
  } else {
    // ================= gold block (one per batch-group) =================
    const int grp = blockIdx.x - chainBlocks;
    const int tid = threadIdx.x;
    const int m   = tid & 15;
    const int h8  = tid >> 4;                // 0..7 across both waves
    const int bglob = grp * GB + m;
    const int* tg = tags + bglob * TT;
    const float* fg = feats + (size_t)bglob * TT * KK;

    float gs = 0.f;
    #pragma unroll 8
    for (int tt = 1 + h8; tt < TT; tt += 8) {
      const int tc = tg[tt];
      const int tp = tg[tt - 1];
      gs += trans[tc * KK + tp] + fg[(size_t)tt * KK + tc];
    }
    gs += __shfl_xor(gs, 16);
    gs += __shfl_xor(gs, 32);
    // lanes<16 of each wave hold the per-m sum over its 4 h8 values
    if (tid >= 64 && (tid & 63) < 16) gpart[tid & 15] = gs;
    __syncthreads();
    if (tid < 16) atomicAdd(&diff[grp * GB + tid], -(gs + gpart[tid]));
  }
}

__global__ __launch_bounds__(1024) void reduce_mean_kernel(
    const float* __restrict__ diff, float* __restrict__ out)
{
  __shared__ float part[16];
  const int tid = threadIdx.x;
  float v = diff[tid];
  #pragma unroll
  for (int off = 32; off; off >>= 1) v += __shfl_xor(v, off);
  if ((tid & 63) == 0) part[tid >> 6] = v;
  __syncthreads();
  if (tid < 16) {
    float s = part[tid];
    #pragma unroll
    for (int off = 8; off; off >>= 1) s += __shfl_xor(s, off);
    if (tid == 0) out[0] = s * (1.0f / 1024.0f);
  }
}

extern "C" void kernel_launch(void* const* d_in, const int* in_sizes, int n_in,
                              void* d_out, int out_size, void* d_ws, size_t ws_size,
                              hipStream_t stream) {
  const float* feats = (const float*)d_in[0];
  const int*   tags  = (const int*)d_in[1];
  const float* trans = (const float*)d_in[2];
  float* out  = (float*)d_out;
  float* diff = (float*)d_ws;                          // 4 KB
  uint4* frags = (uint4*)((char*)d_ws + 4096);         // 32 KB fragment images

  zero_diff_kernel<<<dim3(1), dim3(1024), 0, stream>>>(diff);
  prep_kernel<<<dim3(1), dim3(128), 0, stream>>>(trans, frags);
  crf_seg_kernel<<<dim3(64 * NJ + 64), dim3(128), 0, stream>>>(feats, tags, trans, frags, diff);
  reduce_mean_kernel<<<dim3(1), dim3(1024), 0, stream>>>(diff, out);
}